// Round 1
// baseline (52456.110 us; speedup 1.0000x reference)
//
#include <hip/hip_runtime.h>
#include <hip/hip_bf16.h>

typedef __attribute__((ext_vector_type(8))) short bh8;     // 8 bf16 (4 VGPRs)
typedef __attribute__((ext_vector_type(4))) float fx4;     // MFMA C/D
typedef __attribute__((ext_vector_type(4))) unsigned int ux4;

#define S_LEN 2048
#define OUTBASE 16777216   // 8*2048*1024

__device__ __forceinline__ unsigned short f2bf(float f) {
  __hip_bfloat16 h = __float2bfloat16(f);
  unsigned short u; __builtin_memcpy(&u, &h, 2); return u;
}
__device__ __forceinline__ float bf2f(unsigned short u) {
  __hip_bfloat16 h; __builtin_memcpy(&h, &u, 2); return __bfloat162float(h);
}

// ---------------- prep: transpose + bf16-convert weights ----------------
// WxT[gate*1024+c][k] = Wgate[k][c]      (k<1024)
// WhT[gate*1024+c][k] = Wgate[1024+k][c]
// WegT[c][k] = Weg[k][c]
__global__ __launch_bounds__(256) void prep_w(
    const float* __restrict__ Wi, const float* __restrict__ Wf,
    const float* __restrict__ Wg, const float* __restrict__ Wo,
    const float* __restrict__ Weg,
    __hip_bfloat16* __restrict__ WxT, __hip_bfloat16* __restrict__ WhT,
    __hip_bfloat16* __restrict__ WegT) {
  __shared__ float tile[32][33];
  const int z = blockIdx.z;
  const float* src = (z==0)?Wi:(z==1)?Wf:(z==2)?Wg:(z==3)?Wo:Weg;
  const int kbase = blockIdx.y * 32, cbase = blockIdx.x * 32;
  if (z == 4 && kbase >= 1024) return;
  const int tx = threadIdx.x, ty = threadIdx.y;
#pragma unroll
  for (int rr = 0; rr < 4; ++rr)
    tile[ty*4+rr][tx] = src[(size_t)(kbase + ty*4+rr)*1024 + cbase + tx];
  __syncthreads();
#pragma unroll
  for (int rr = 0; rr < 4; ++rr) {
    int c = cbase + ty*4+rr;
    int k = kbase + tx;
    __hip_bfloat16 v = __float2bfloat16(tile[tx][ty*4+rr]);
    if (z < 4) {
      if (k < 1024) WxT[(size_t)(z*1024 + c)*1024 + k] = v;
      else          WhT[(size_t)(z*1024 + c)*1024 + (k-1024)] = v;
    } else {
      WegT[(size_t)c*1024 + k] = v;
    }
  }
}

// ---------------- init: zero h/g broadcast buffers, flags; build bias concat ----
__global__ __launch_bounds__(256) void init_k(
    __hip_bfloat16* h_buf, __hip_bfloat16* g_buf, int* flags,
    const float* __restrict__ bi, const float* __restrict__ bfv,
    const float* __restrict__ bg, const float* __restrict__ bo,
    float* __restrict__ bcat) {
  int t = blockIdx.x * 256 + threadIdx.x;
  if (t < 16384) { h_buf[t] = __float2bfloat16(0.f); g_buf[t] = __float2bfloat16(0.f); }
  if (t < 256) flags[t] = 0;
  if (t < 4096) {
    float v = (t < 1024) ? bi[t] : (t < 2048) ? bfv[t-1024]
            : (t < 3072) ? bg[t-2048] : bo[t-3072];
    bcat[t] = v;
  }
}

// ---------------- convert x to bf16 ----------------
__global__ __launch_bounds__(256) void conv_x(const float* __restrict__ x,
                                              __hip_bfloat16* __restrict__ xbf) {
  size_t i = ((size_t)blockIdx.x * 256 + threadIdx.x) * 8;
  fx4 a = *reinterpret_cast<const fx4*>(x + i);
  fx4 b = *reinterpret_cast<const fx4*>(x + i + 4);
  unsigned short o[8];
#pragma unroll
  for (int u = 0; u < 4; ++u) { o[u] = f2bf(a[u]); o[4+u] = f2bf(b[u]); }
  bh8 v; __builtin_memcpy(&v, o, 16);
  *reinterpret_cast<bh8*>(xbf + i) = v;
}

// ---------------- phase-1 GEMM: XG[s*8+b][c] = x @ Wx + bias (bf16) ----------------
// A = xbf[16384][1024], B^T = WxT[4096][1024], 128x128 tile, BK=64, 4 waves.
__global__ __launch_bounds__(256) void gemm_x(
    const __hip_bfloat16* __restrict__ xbf,
    const __hip_bfloat16* __restrict__ WxT,
    const float* __restrict__ bcat,
    __hip_bfloat16* __restrict__ XG) {
  __shared__ bh8 ldsv[2048];                 // 32 KB: As 16KB @0, Bs 16KB @16384
  char* lds = reinterpret_cast<char*>(ldsv);
  const int tid = threadIdx.x;
  const int bn = blockIdx.x, bm = blockIdx.y;
  const int lane = tid & 63, wid = tid >> 6;
  const int wr = wid >> 1, wc = wid & 1;
  fx4 acc[4][4] = {};
  for (int kb = 0; kb < 16; ++kb) {
    __syncthreads();
#pragma unroll
    for (int c = 0; c < 4; ++c) {
      int cid = tid + 256 * c;               // 0..1023
      int r = cid >> 3, kc = cid & 7;
      bh8 va = *reinterpret_cast<const bh8*>(xbf + (size_t)(bm*128 + r)*1024 + kb*64 + kc*8);
      int off = (r*128 + kc*16) ^ ((r & 7) << 4);
      *reinterpret_cast<bh8*>(lds + off) = va;
      bh8 vb = *reinterpret_cast<const bh8*>(WxT + (size_t)(bn*128 + r)*1024 + kb*64 + kc*8);
      *reinterpret_cast<bh8*>(lds + 16384 + off) = vb;
    }
    __syncthreads();
#pragma unroll
    for (int ks = 0; ks < 2; ++ks) {
      bh8 af[4], bfr[4];
      int ac = ks*64 + (lane >> 4) * 16;     // byte offset in 128B row
#pragma unroll
      for (int i = 0; i < 4; ++i) {
        int ar = wr*64 + i*16 + (lane & 15);
        af[i] = *reinterpret_cast<const bh8*>(lds + ((ar*128 + ac) ^ ((ar & 7) << 4)));
        int br = wc*64 + i*16 + (lane & 15);
        bfr[i] = *reinterpret_cast<const bh8*>(lds + 16384 + ((br*128 + ac) ^ ((br & 7) << 4)));
      }
#pragma unroll
      for (int i = 0; i < 4; ++i)
#pragma unroll
        for (int jn = 0; jn < 4; ++jn)
          acc[i][jn] = __builtin_amdgcn_mfma_f32_16x16x32_bf16(af[i], bfr[jn], acc[i][jn], 0, 0, 0);
    }
  }
  // epilogue: D col = lane&15, row = (lane>>4)*4 + jj  [guide §3, HW-verified]
#pragma unroll
  for (int i = 0; i < 4; ++i) {
    int rbase = bm*128 + wr*64 + i*16 + (lane >> 4) * 4;
#pragma unroll
    for (int jn = 0; jn < 4; ++jn) {
      int col = bn*128 + wc*64 + jn*16 + (lane & 15);
      float bias = bcat[col];
#pragma unroll
      for (int jj = 0; jj < 4; ++jj) {
        int r = rbase + jj;
        int b = r >> 11, s = r & 2047;
        XG[(size_t)(s*8 + b)*4096 + col] = __float2bfloat16(acc[i][jn][jj] + bias);
      }
    }
  }
}

// ---------------- persistent recurrence kernel ----------------
struct __align__(16) RecurLds {
  short wa[16 * 1024];        // 32KB gate-weight slice, col-major, xor-swizzled
  short weg[4 * 1024];        // 8KB Weg slice
  float exk[4][8][16];        // K-split partial D
  float act[16][8];           // activated gates [col][b]
  unsigned short pk[8][4];    // bf16 pack staging
  unsigned short xg[2][8][16];// XG slice double-buffer
};

__device__ __forceinline__ void gbar(int* flags, int q, int tid, int j) {
  __syncthreads();  // all waves done; vmcnt drained before barrier (HIP semantics)
  if (tid == 0) {
    int old = __hip_atomic_fetch_add(&flags[(j & 7) * 16], 1,
                                     __ATOMIC_ACQ_REL, __HIP_MEMORY_SCOPE_AGENT);
    if (old == 32 * (q + 1) - 1)
      __hip_atomic_fetch_add(&flags[128], 1, __ATOMIC_RELEASE, __HIP_MEMORY_SCOPE_AGENT);
    while (__hip_atomic_load(&flags[128], __ATOMIC_RELAXED, __HIP_MEMORY_SCOPE_AGENT) < 8 * (q + 1))
      __builtin_amdgcn_s_sleep(2);
    __builtin_amdgcn_fence(__ATOMIC_ACQUIRE, "agent");
  }
  __syncthreads();
}

__global__ __launch_bounds__(256, 1) void recur(
    const __hip_bfloat16* __restrict__ WhT,
    const __hip_bfloat16* __restrict__ WegT,
    const __hip_bfloat16* __restrict__ XG,
    const float* __restrict__ beg,
    __hip_bfloat16* h_buf, __hip_bfloat16* g_buf,
    int* flags, float* d_out) {
  __shared__ RecurLds L;
  const int j = blockIdx.x;            // 0..255, owns h-cols [4j,4j+4)
  const int tid = threadIdx.x;
  const int w = tid >> 6, lane = tid & 63;
  const int col16 = lane & 15, rgrp = lane >> 4;

  // load weight slices into LDS (col-major, xor-swizzled per 16B chunk)
  for (int cid = tid; cid < 2048; cid += 256) {   // 16 cols x 128 chunks
    int cc = cid >> 7, kc = cid & 127;
    int gate = cc >> 2, c = cc & 3;
    bh8 v = *reinterpret_cast<const bh8*>(&WhT[((size_t)(gate*1024 + j*4 + c))*1024 + kc*8]);
    *reinterpret_cast<bh8*>(reinterpret_cast<char*>(L.wa) + ((cc*2048 + kc*16) ^ ((cc & 7) << 4))) = v;
  }
  for (int cid = tid; cid < 512; cid += 256) {    // 4 cols x 128 chunks
    int cc = cid >> 7, kc = cid & 127;
    bh8 v = *reinterpret_cast<const bh8*>(&WegT[((size_t)(j*4 + cc))*1024 + kc*8]);
    *reinterpret_cast<bh8*>(reinterpret_cast<char*>(L.weg) + ((cc*2048 + kc*16) ^ (cc << 4))) = v;
  }
  float begv = 0.f;
  float c_st = 0.f, n_st = 0.f, i_v = 0.f, f_v = 0.f, o_v = 0.f, c_new = 0.f;
  if (tid < 32) begv = beg[j*4 + (tid & 3)];
  if (tid < 32) {  // stage XG[0]
    int b = tid >> 2, gate = tid & 3;
    unsigned long long v = *reinterpret_cast<const unsigned long long*>(
        &XG[((size_t)b)*4096 + gate*1024 + j*4]);
    *reinterpret_cast<unsigned long long*>(&L.xg[0][b][gate*4]) = v;
  }
  __syncthreads();

#pragma unroll 1
  for (int t = 0; t < S_LEN; ++t) {
    // prefetch next step's XG slice (independent of barriers)
    if (t < S_LEN - 1 && tid < 32) {
      int b = tid >> 2, gate = tid & 3;
      unsigned long long v = *reinterpret_cast<const unsigned long long*>(
          &XG[((size_t)(t+1)*8 + b)*4096 + gate*1024 + j*4]);
      *reinterpret_cast<unsigned long long*>(&L.xg[(t+1) & 1][b][gate*4]) = v;
    }
    // ---- phase A: preacts = h @ Wh (K split over 4 waves) ----
    unsigned int a0[8][4];
    {
      const unsigned int* hb32 = reinterpret_cast<const unsigned int*>(h_buf);
#pragma unroll
      for (int ks = 0; ks < 8; ++ks) {
        int eo = col16*1024 + w*256 + ks*32 + rgrp*8;
        const unsigned int* p = hb32 + (eo >> 1);
#pragma unroll
        for (int u = 0; u < 4; ++u)
          a0[ks][u] = __hip_atomic_load(const_cast<unsigned int*>(p + u),
                                        __ATOMIC_RELAXED, __HIP_MEMORY_SCOPE_AGENT);
      }
    }
    fx4 d = {0.f, 0.f, 0.f, 0.f};
#pragma unroll
    for (int ks = 0; ks < 8; ++ks) {
      int koff = w*256 + ks*32 + rgrp*8;
      bh8 bfr = *reinterpret_cast<const bh8*>(
          reinterpret_cast<char*>(L.wa) + ((col16*2048 + koff*2) ^ ((col16 & 7) << 4)));
      ux4 uv = { a0[ks][0], a0[ks][1], a0[ks][2], a0[ks][3] };
      bh8 afr = __builtin_bit_cast(bh8, uv);
      d = __builtin_amdgcn_mfma_f32_16x16x32_bf16(afr, bfr, d, 0, 0, 0);
    }
    if (rgrp < 2) {
#pragma unroll
      for (int jj = 0; jj < 4; ++jj) L.exk[w][rgrp*4 + jj][col16] = d[jj];
    }
    __syncthreads();
    if (tid < 128) {  // reduce K-partials + XG, activate
      int cc = tid & 15, b = tid >> 4;
      float s = L.exk[0][b][cc] + L.exk[1][b][cc] + L.exk[2][b][cc] + L.exk[3][b][cc];
      s += bf2f(L.xg[t & 1][b][cc]);
      float a = ((cc >> 2) == 2) ? tanhf(s) : 1.f / (1.f + expf(-s));
      L.act[cc][b] = a;
    }
    __syncthreads();
    if (tid < 32) {   // state update (c), stage g for broadcast
      int b = tid >> 2, c = tid & 3;
      i_v = L.act[c][b]; f_v = L.act[4 + c][b];
      float g_v = L.act[8 + c][b]; o_v = L.act[12 + c][b];
      c_new = f_v * c_st + i_v * g_v; c_st = c_new;
      L.pk[b][c] = f2bf(g_v);
    }
    if (tid < 16) {   // pack 2x bf16 -> u32, coherent store
      int b = tid >> 1, hh = tid & 1;
      unsigned int v = (unsigned int)L.pk[b][2*hh] | ((unsigned int)L.pk[b][2*hh + 1] << 16);
      __hip_atomic_store(reinterpret_cast<unsigned int*>(g_buf + (size_t)b*1024 + j*4 + 2*hh),
                         v, __ATOMIC_RELAXED, __HIP_MEMORY_SCOPE_AGENT);
    }
    gbar(flags, 2*t, tid, j);
    // ---- phase B: e = g @ Weg (cols 4j..4j+4), n/h update ----
    {
      const unsigned int* gb32 = reinterpret_cast<const unsigned int*>(g_buf);
#pragma unroll
      for (int ks = 0; ks < 8; ++ks) {
        int eo = col16*1024 + w*256 + ks*32 + rgrp*8;
        const unsigned int* p = gb32 + (eo >> 1);
#pragma unroll
        for (int u = 0; u < 4; ++u)
          a0[ks][u] = __hip_atomic_load(const_cast<unsigned int*>(p + u),
                                        __ATOMIC_RELAXED, __HIP_MEMORY_SCOPE_AGENT);
      }
    }
    fx4 d2 = {0.f, 0.f, 0.f, 0.f};
#pragma unroll
    for (int ks = 0; ks < 8; ++ks) {
      int koff = w*256 + ks*32 + rgrp*8;
      bh8 bfr;
      if (col16 < 4)
        bfr = *reinterpret_cast<const bh8*>(
            reinterpret_cast<char*>(L.weg) + ((col16*2048 + koff*2) ^ (col16 << 4)));
      else
        bfr = bh8{0, 0, 0, 0, 0, 0, 0, 0};
      ux4 uv = { a0[ks][0], a0[ks][1], a0[ks][2], a0[ks][3] };
      bh8 afr = __builtin_bit_cast(bh8, uv);
      d2 = __builtin_amdgcn_mfma_f32_16x16x32_bf16(afr, bfr, d2, 0, 0, 0);
    }
    if (rgrp < 2 && col16 < 4) {
#pragma unroll
      for (int jj = 0; jj < 4; ++jj) L.exk[w][rgrp*4 + jj][col16] = d2[jj];
    }
    __syncthreads();
    if (tid < 32) {
      int b = tid >> 2, c = tid & 3;
      float s = L.exk[0][b][c] + L.exk[1][b][c] + L.exk[2][b][c] + L.exk[3][b][c] + begv;
      float e = expf(s);
      float n_new = f_v * n_st + i_v * e; n_st = n_new;
      float h_new = o_v * (c_new / n_new);
      d_out[((size_t)b*2048 + t)*1024 + j*4 + c] = h_new;   // h history (fp32, pre-LN)
      if (t == S_LEN - 1) {
        d_out[OUTBASE +         (size_t)b*1024 + j*4 + c] = h_new;  // h_f
        d_out[OUTBASE +  8192 + (size_t)b*1024 + j*4 + c] = c_new;  // c_f
        d_out[OUTBASE + 16384 + (size_t)b*1024 + j*4 + c] = n_new;  // n_f
      }
      L.pk[b][c] = f2bf(h_new);
    }
    if (tid < 16) {
      int b = tid >> 1, hh = tid & 1;
      unsigned int v = (unsigned int)L.pk[b][2*hh] | ((unsigned int)L.pk[b][2*hh + 1] << 16);
      __hip_atomic_store(reinterpret_cast<unsigned int*>(h_buf + (size_t)b*1024 + j*4 + 2*hh),
                         v, __ATOMIC_RELAXED, __HIP_MEMORY_SCOPE_AGENT);
    }
    if (t < S_LEN - 1) gbar(flags, 2*t + 1, tid, j);
  }
}

// ---------------- residual + LayerNorm (in-place on d_out) ----------------
__global__ __launch_bounds__(256) void ln_k(const float* __restrict__ x,
                                            const float* __restrict__ gamma,
                                            const float* __restrict__ beta,
                                            float* __restrict__ out) {
  const int r = blockIdx.x, tid = threadIdx.x;
  float* orow = out + (size_t)r * 1024;
  const float* xrow = x + (size_t)r * 1024;
  fx4 h4 = *reinterpret_cast<const fx4*>(orow + tid*4);
  fx4 x4 = *reinterpret_cast<const fx4*>(xrow + tid*4);
  fx4 y = h4 + x4;
  float s = y[0] + y[1] + y[2] + y[3];
  float s2 = y[0]*y[0] + y[1]*y[1] + y[2]*y[2] + y[3]*y[3];
#pragma unroll
  for (int m = 1; m < 64; m <<= 1) { s += __shfl_xor(s, m, 64); s2 += __shfl_xor(s2, m, 64); }
  __shared__ float ps[4], ps2[4], stats[2];
  if ((tid & 63) == 0) { ps[tid >> 6] = s; ps2[tid >> 6] = s2; }
  __syncthreads();
  if (tid == 0) {
    float t1 = ps[0] + ps[1] + ps[2] + ps[3];
    float t2 = ps2[0] + ps2[1] + ps2[2] + ps2[3];
    float mu = t1 * (1.f / 1024.f);
    float var = t2 * (1.f / 1024.f) - mu * mu;
    stats[0] = mu; stats[1] = rsqrtf(var + 1e-5f);
  }
  __syncthreads();
  float mu = stats[0], rs = stats[1];
  fx4 g4 = *reinterpret_cast<const fx4*>(gamma + tid*4);
  fx4 b4 = *reinterpret_cast<const fx4*>(beta + tid*4);
  fx4 o4;
#pragma unroll
  for (int u = 0; u < 4; ++u) o4[u] = (y[u] - mu) * rs * g4[u] + b4[u];
  *reinterpret_cast<fx4*>(orow + tid*4) = o4;
}

extern "C" void kernel_launch(void* const* d_in, const int* in_sizes, int n_in,
                              void* d_out, int out_size, void* d_ws, size_t ws_size,
                              hipStream_t stream) {
  const float* x    = (const float*)d_in[0];
  const float* Wi   = (const float*)d_in[1];
  const float* bi   = (const float*)d_in[2];
  const float* Wf   = (const float*)d_in[3];
  const float* bfv  = (const float*)d_in[4];
  const float* Wg   = (const float*)d_in[5];
  const float* bg   = (const float*)d_in[6];
  const float* Wo   = (const float*)d_in[7];
  const float* bo   = (const float*)d_in[8];
  const float* Weg  = (const float*)d_in[9];
  const float* beg  = (const float*)d_in[10];
  const float* gamma= (const float*)d_in[11];
  const float* beta = (const float*)d_in[12];
  float* out = (float*)d_out;
  char* ws = (char*)d_ws;

  __hip_bfloat16* XG   = (__hip_bfloat16*)(ws);                    // 134217728 B
  __hip_bfloat16* xbf  = (__hip_bfloat16*)(ws + 134217728ull);     //  33554432 B
  __hip_bfloat16* WxT  = (__hip_bfloat16*)(ws + 167772160ull);     //   8388608 B
  __hip_bfloat16* WhT  = (__hip_bfloat16*)(ws + 176160768ull);     //   8388608 B
  __hip_bfloat16* WegT = (__hip_bfloat16*)(ws + 184549376ull);     //   2097152 B
  float* bcat          = (float*)(ws + 186646528ull);              //     16384 B
  __hip_bfloat16* hbuf = (__hip_bfloat16*)(ws + 186662912ull);     //     32768 B
  __hip_bfloat16* gbuf = (__hip_bfloat16*)(ws + 186695680ull);     //     32768 B
  int* flags           = (int*)(ws + 186728448ull);                //      1024 B

  prep_w<<<dim3(32, 64, 5), dim3(32, 8), 0, stream>>>(Wi, Wf, Wg, Wo, Weg, WxT, WhT, WegT);
  init_k<<<dim3(64), dim3(256), 0, stream>>>(hbuf, gbuf, flags, bi, bfv, bg, bo, bcat);
  conv_x<<<dim3(8192), dim3(256), 0, stream>>>(x, xbf);
  gemm_x<<<dim3(32, 128), dim3(256), 0, stream>>>(xbf, WxT, bcat, XG);
  recur<<<dim3(256), dim3(256), 0, stream>>>(WhT, WegT, XG, beg, hbuf, gbuf, flags, out);
  ln_k<<<dim3(16384), dim3(256), 0, stream>>>(x, gamma, beta, out);
}

// Round 2
// 21981.245 us; speedup vs baseline: 2.3864x; 2.3864x over previous
//
#include <hip/hip_runtime.h>
#include <hip/hip_bf16.h>

typedef __attribute__((ext_vector_type(8))) short bh8;     // 8 bf16 (4 VGPRs)
typedef __attribute__((ext_vector_type(4))) float fx4;     // MFMA C/D
typedef __attribute__((ext_vector_type(4))) unsigned int ux4;
typedef unsigned int u32;
typedef unsigned long long u64;

#define S_LEN 2048
#define OUTBASE 16777216   // 8*2048*1024

__device__ __forceinline__ unsigned short f2bf(float f) {
  __hip_bfloat16 h = __float2bfloat16(f);
  unsigned short u; __builtin_memcpy(&u, &h, 2); return u;
}
__device__ __forceinline__ float bf2f(unsigned short u) {
  __hip_bfloat16 h; __builtin_memcpy(&h, &u, 2); return __bfloat162float(h);
}

// ---------------- prep: transpose + bf16-convert weights ----------------
__global__ __launch_bounds__(256) void prep_w(
    const float* __restrict__ Wi, const float* __restrict__ Wf,
    const float* __restrict__ Wg, const float* __restrict__ Wo,
    const float* __restrict__ Weg,
    __hip_bfloat16* __restrict__ WxT, __hip_bfloat16* __restrict__ WhT,
    __hip_bfloat16* __restrict__ WegT) {
  __shared__ float tile[32][33];
  const int z = blockIdx.z;
  const float* src = (z==0)?Wi:(z==1)?Wf:(z==2)?Wg:(z==3)?Wo:Weg;
  const int kbase = blockIdx.y * 32, cbase = blockIdx.x * 32;
  if (z == 4 && kbase >= 1024) return;
  const int tx = threadIdx.x, ty = threadIdx.y;
#pragma unroll
  for (int rr = 0; rr < 4; ++rr)
    tile[ty*4+rr][tx] = src[(size_t)(kbase + ty*4+rr)*1024 + cbase + tx];
  __syncthreads();
#pragma unroll
  for (int rr = 0; rr < 4; ++rr) {
    int c = cbase + ty*4+rr;
    int k = kbase + tx;
    __hip_bfloat16 v = __float2bfloat16(tile[tx][ty*4+rr]);
    if (z < 4) {
      if (k < 1024) WxT[(size_t)(z*1024 + c)*1024 + k] = v;
      else          WhT[(size_t)(z*1024 + c)*1024 + (k-1024)] = v;
    } else {
      WegT[(size_t)c*1024 + k] = v;
    }
  }
}

// ---------------- init: zero tagged h/g exchange buffers; build bias concat ----
__global__ __launch_bounds__(256) void init_k(
    u32* h_tag, u32* g_tag,
    const float* __restrict__ bi, const float* __restrict__ bfv,
    const float* __restrict__ bg, const float* __restrict__ bo,
    float* __restrict__ bcat) {
  int t = blockIdx.x * 256 + threadIdx.x;
  if (t < 8192) { h_tag[t] = 0u; g_tag[t] = 0u; }   // value bf16(0), tag 0
  if (t < 4096) {
    float v = (t < 1024) ? bi[t] : (t < 2048) ? bfv[t-1024]
            : (t < 3072) ? bg[t-2048] : bo[t-3072];
    bcat[t] = v;
  }
}

// ---------------- convert x to bf16 ----------------
__global__ __launch_bounds__(256) void conv_x(const float* __restrict__ x,
                                              __hip_bfloat16* __restrict__ xbf) {
  size_t i = ((size_t)blockIdx.x * 256 + threadIdx.x) * 8;
  fx4 a = *reinterpret_cast<const fx4*>(x + i);
  fx4 b = *reinterpret_cast<const fx4*>(x + i + 4);
  unsigned short o[8];
#pragma unroll
  for (int u = 0; u < 4; ++u) { o[u] = f2bf(a[u]); o[4+u] = f2bf(b[u]); }
  bh8 v; __builtin_memcpy(&v, o, 16);
  *reinterpret_cast<bh8*>(xbf + i) = v;
}

// ---------------- phase-1 GEMM: XG[s*8+b][c] = x @ Wx + bias (bf16) ----------------
__global__ __launch_bounds__(256) void gemm_x(
    const __hip_bfloat16* __restrict__ xbf,
    const __hip_bfloat16* __restrict__ WxT,
    const float* __restrict__ bcat,
    __hip_bfloat16* __restrict__ XG) {
  __shared__ bh8 ldsv[2048];                 // 32 KB
  char* lds = reinterpret_cast<char*>(ldsv);
  const int tid = threadIdx.x;
  const int bn = blockIdx.x, bm = blockIdx.y;
  const int lane = tid & 63, wid = tid >> 6;
  const int wr = wid >> 1, wc = wid & 1;
  fx4 acc[4][4] = {};
  for (int kb = 0; kb < 16; ++kb) {
    __syncthreads();
#pragma unroll
    for (int c = 0; c < 4; ++c) {
      int cid = tid + 256 * c;
      int r = cid >> 3, kc = cid & 7;
      bh8 va = *reinterpret_cast<const bh8*>(xbf + (size_t)(bm*128 + r)*1024 + kb*64 + kc*8);
      int off = (r*128 + kc*16) ^ ((r & 7) << 4);
      *reinterpret_cast<bh8*>(lds + off) = va;
      bh8 vb = *reinterpret_cast<const bh8*>(WxT + (size_t)(bn*128 + r)*1024 + kb*64 + kc*8);
      *reinterpret_cast<bh8*>(lds + 16384 + off) = vb;
    }
    __syncthreads();
#pragma unroll
    for (int ks = 0; ks < 2; ++ks) {
      bh8 af[4], bfr[4];
      int ac = ks*64 + (lane >> 4) * 16;
#pragma unroll
      for (int i = 0; i < 4; ++i) {
        int ar = wr*64 + i*16 + (lane & 15);
        af[i] = *reinterpret_cast<const bh8*>(lds + ((ar*128 + ac) ^ ((ar & 7) << 4)));
        int br = wc*64 + i*16 + (lane & 15);
        bfr[i] = *reinterpret_cast<const bh8*>(lds + 16384 + ((br*128 + ac) ^ ((br & 7) << 4)));
      }
#pragma unroll
      for (int i = 0; i < 4; ++i)
#pragma unroll
        for (int jn = 0; jn < 4; ++jn)
          acc[i][jn] = __builtin_amdgcn_mfma_f32_16x16x32_bf16(af[i], bfr[jn], acc[i][jn], 0, 0, 0);
    }
  }
#pragma unroll
  for (int i = 0; i < 4; ++i) {
    int rbase = bm*128 + wr*64 + i*16 + (lane >> 4) * 4;
#pragma unroll
    for (int jn = 0; jn < 4; ++jn) {
      int col = bn*128 + wc*64 + jn*16 + (lane & 15);
      float bias = bcat[col];
#pragma unroll
      for (int jj = 0; jj < 4; ++jj) {
        int r = rbase + jj;
        int b = r >> 11, s = r & 2047;
        XG[(size_t)(s*8 + b)*4096 + col] = __float2bfloat16(acc[i][jn][jj] + bias);
      }
    }
  }
}

// ---------------- persistent recurrence kernel (tagged-data exchange) ----------------
struct __align__(16) RecurLds {
  short wa[16 * 1024];        // 32KB gate-weight slice, col-major, xor-swizzled
  short weg[4 * 1024];        // 8KB Weg slice
  float exk[4][8][16];        // K-split partial D
  unsigned short xg[2][8][16];// XG slice double-buffer
};

// Poll 8 chunks of 8 tagged u32 each (64 bf16) until every tag == etag; pack
// value-halves into MFMA A-fragment words. Tag travels WITH data in the same
// 4B word -> no fences, no flag traffic, the poll IS the barrier.
__device__ __forceinline__ void pollread(const u64* base, u32 etag, bool active,
                                         u32 (&a0)[8][4]) {
#pragma unroll
  for (int ks = 0; ks < 8; ++ks)
#pragma unroll
    for (int u = 0; u < 4; ++u) a0[ks][u] = 0;
  if (!active) return;
  u32 pend = 0xFFu;
  while (pend) {
#pragma unroll
    for (int ks = 0; ks < 8; ++ks) {
      if (pend & (1u << ks)) {
        u64 q[4];
#pragma unroll
        for (int u = 0; u < 4; ++u)
          q[u] = __hip_atomic_load(const_cast<u64*>(base + ks*16 + u),
                                   __ATOMIC_RELAXED, __HIP_MEMORY_SCOPE_AGENT);
        u32 bad = 0;
#pragma unroll
        for (int u = 0; u < 4; ++u) {
          u32 lo = (u32)q[u], hi = (u32)(q[u] >> 32);
          bad |= ((lo ^ etag) | (hi ^ etag)) & 0xFFFFu;
        }
        if (!bad) {
          pend &= ~(1u << ks);
#pragma unroll
          for (int u = 0; u < 4; ++u) {
            u32 lo = (u32)q[u], hi = (u32)(q[u] >> 32);
            a0[ks][u] = (lo >> 16) | (hi & 0xFFFF0000u);
          }
        }
      }
    }
  }
}

__global__ __launch_bounds__(256, 1) void recur(
    const __hip_bfloat16* __restrict__ WhT,
    const __hip_bfloat16* __restrict__ WegT,
    const __hip_bfloat16* __restrict__ XG,
    const float* __restrict__ beg,
    u32* h_tag, u32* g_tag, float* d_out) {
  __shared__ RecurLds L;
  const int j = blockIdx.x;            // 0..255, owns h-cols [4j,4j+4)
  const int tid = threadIdx.x;
  const int w = tid >> 6, lane = tid & 63;
  const int col16 = lane & 15, rgrp = lane >> 4;

  // load weight slices into LDS (col-major, xor-swizzled per 16B chunk)
  for (int cid = tid; cid < 2048; cid += 256) {
    int cc = cid >> 7, kc = cid & 127;
    int gate = cc >> 2, c = cc & 3;
    bh8 v = *reinterpret_cast<const bh8*>(&WhT[((size_t)(gate*1024 + j*4 + c))*1024 + kc*8]);
    *reinterpret_cast<bh8*>(reinterpret_cast<char*>(L.wa) + ((cc*2048 + kc*16) ^ ((cc & 7) << 4))) = v;
  }
  for (int cid = tid; cid < 512; cid += 256) {
    int cc = cid >> 7, kc = cid & 127;
    bh8 v = *reinterpret_cast<const bh8*>(&WegT[((size_t)(j*4 + cc))*1024 + kc*8]);
    *reinterpret_cast<bh8*>(reinterpret_cast<char*>(L.weg) + ((cc*2048 + kc*16) ^ (cc << 4))) = v;
  }
  float begv = 0.f, c_st = 0.f, n_st = 0.f;
  if (tid < 32) begv = beg[j*4 + (tid & 3)];
  if (tid < 32) {  // stage XG[0]
    int b = tid >> 2, gate = tid & 3;
    u64 v = *reinterpret_cast<const u64*>(&XG[((size_t)b)*4096 + gate*1024 + j*4]);
    *reinterpret_cast<u64*>(&L.xg[0][b][gate*4]) = v;
  }
  __syncthreads();

  const bool act_lane = (col16 < 8);
  const u64* hbase = reinterpret_cast<const u64*>(h_tag) + (col16*512 + w*128 + rgrp*4);
  const u64* gbase = reinterpret_cast<const u64*>(g_tag) + (col16*512 + w*128 + rgrp*4);
  const int b32 = tid >> 2, c32 = tid & 3;   // for tid<32 roles

#pragma unroll 1
  for (int t = 0; t < S_LEN; ++t) {
    // prefetch next step's XG slice (plain cached loads; XG is read-only)
    if (t < S_LEN - 1 && tid < 32) {
      u64 v = *reinterpret_cast<const u64*>(
          &XG[((size_t)(t+1)*8 + b32)*4096 + c32*1024 + j*4]);
      *reinterpret_cast<u64*>(&L.xg[(t+1) & 1][b32][c32*4]) = v;
    }
    // ---- phase A: preacts = h @ Wh (K split over 4 waves) ----
    u32 a0[8][4];
    pollread(hbase, (u32)t, act_lane, a0);
    fx4 d = {0.f, 0.f, 0.f, 0.f};
#pragma unroll
    for (int ks = 0; ks < 8; ++ks) {
      int koff = w*256 + ks*32 + rgrp*8;
      bh8 bfr = *reinterpret_cast<const bh8*>(
          reinterpret_cast<char*>(L.wa) + ((col16*2048 + koff*2) ^ ((col16 & 7) << 4)));
      ux4 uv = { a0[ks][0], a0[ks][1], a0[ks][2], a0[ks][3] };
      bh8 afr = __builtin_bit_cast(bh8, uv);
      d = __builtin_amdgcn_mfma_f32_16x16x32_bf16(afr, bfr, d, 0, 0, 0);
    }
    __syncthreads();                       // prev consumers of exk done
    if (rgrp < 2) {
#pragma unroll
      for (int jj = 0; jj < 4; ++jj) L.exk[w][rgrp*4 + jj][col16] = d[jj];
    }
    __syncthreads();
    float i_v = 0.f, f_v = 0.f, o_v = 0.f, c_new = 0.f;
    if (tid < 32) {   // gates, c-state, tagged-g broadcast store
      float si = L.exk[0][b32][c32]      + L.exk[1][b32][c32]      + L.exk[2][b32][c32]      + L.exk[3][b32][c32]      + bf2f(L.xg[t & 1][b32][c32]);
      float sf = L.exk[0][b32][4 + c32]  + L.exk[1][b32][4 + c32]  + L.exk[2][b32][4 + c32]  + L.exk[3][b32][4 + c32]  + bf2f(L.xg[t & 1][b32][4 + c32]);
      float sg = L.exk[0][b32][8 + c32]  + L.exk[1][b32][8 + c32]  + L.exk[2][b32][8 + c32]  + L.exk[3][b32][8 + c32]  + bf2f(L.xg[t & 1][b32][8 + c32]);
      float so = L.exk[0][b32][12 + c32] + L.exk[1][b32][12 + c32] + L.exk[2][b32][12 + c32] + L.exk[3][b32][12 + c32] + bf2f(L.xg[t & 1][b32][12 + c32]);
      i_v = 1.f / (1.f + expf(-si));
      f_v = 1.f / (1.f + expf(-sf));
      float g_v = tanhf(sg);
      o_v = 1.f / (1.f + expf(-so));
      c_new = f_v * c_st + i_v * g_v; c_st = c_new;
      u32 tg = ((u32)f2bf(g_v) << 16) | (u32)(t + 1);
      __hip_atomic_store(&g_tag[b32*1024 + j*4 + c32], tg,
                         __ATOMIC_RELAXED, __HIP_MEMORY_SCOPE_AGENT);
    }
    // ---- phase B: e = g @ Weg (cols 4j..4j+4), n/h update ----
    u32 b0[8][4];
    pollread(gbase, (u32)(t + 1), act_lane, b0);
    fx4 d2 = {0.f, 0.f, 0.f, 0.f};
#pragma unroll
    for (int ks = 0; ks < 8; ++ks) {
      int koff = w*256 + ks*32 + rgrp*8;
      bh8 bfr;
      if (col16 < 4)
        bfr = *reinterpret_cast<const bh8*>(
            reinterpret_cast<char*>(L.weg) + ((col16*2048 + koff*2) ^ (col16 << 4)));
      else
        bfr = bh8{0, 0, 0, 0, 0, 0, 0, 0};
      ux4 uv = { b0[ks][0], b0[ks][1], b0[ks][2], b0[ks][3] };
      bh8 afr = __builtin_bit_cast(bh8, uv);
      d2 = __builtin_amdgcn_mfma_f32_16x16x32_bf16(afr, bfr, d2, 0, 0, 0);
    }
    __syncthreads();                       // phase-A exk consumers done
    if (rgrp < 2 && col16 < 4) {
#pragma unroll
      for (int jj = 0; jj < 4; ++jj) L.exk[w][rgrp*4 + jj][col16] = d2[jj];
    }
    __syncthreads();
    if (tid < 32) {
      float s = L.exk[0][b32][c32] + L.exk[1][b32][c32]
              + L.exk[2][b32][c32] + L.exk[3][b32][c32] + begv;
      float e = expf(s);
      float n_new = f_v * n_st + i_v * e; n_st = n_new;
      float h_new = o_v * (c_new / n_new);
      d_out[((size_t)b32*2048 + t)*1024 + j*4 + c32] = h_new;   // h history (pre-LN)
      if (t == S_LEN - 1) {
        d_out[OUTBASE +         (size_t)b32*1024 + j*4 + c32] = h_new;  // h_f
        d_out[OUTBASE +  8192 + (size_t)b32*1024 + j*4 + c32] = c_new;  // c_f
        d_out[OUTBASE + 16384 + (size_t)b32*1024 + j*4 + c32] = n_new;  // n_f
      }
      u32 th = ((u32)f2bf(h_new) << 16) | (u32)(t + 1);
      __hip_atomic_store(&h_tag[b32*1024 + j*4 + c32], th,
                         __ATOMIC_RELAXED, __HIP_MEMORY_SCOPE_AGENT);
    }
  }
}

// ---------------- residual + LayerNorm (in-place on d_out) ----------------
__global__ __launch_bounds__(256) void ln_k(const float* __restrict__ x,
                                            const float* __restrict__ gamma,
                                            const float* __restrict__ beta,
                                            float* __restrict__ out) {
  const int r = blockIdx.x, tid = threadIdx.x;
  float* orow = out + (size_t)r * 1024;
  const float* xrow = x + (size_t)r * 1024;
  fx4 h4 = *reinterpret_cast<const fx4*>(orow + tid*4);
  fx4 x4 = *reinterpret_cast<const fx4*>(xrow + tid*4);
  fx4 y = h4 + x4;
  float s = y[0] + y[1] + y[2] + y[3];
  float s2 = y[0]*y[0] + y[1]*y[1] + y[2]*y[2] + y[3]*y[3];
#pragma unroll
  for (int m = 1; m < 64; m <<= 1) { s += __shfl_xor(s, m, 64); s2 += __shfl_xor(s2, m, 64); }
  __shared__ float ps[4], ps2[4], stats[2];
  if ((tid & 63) == 0) { ps[tid >> 6] = s; ps2[tid >> 6] = s2; }
  __syncthreads();
  if (tid == 0) {
    float t1 = ps[0] + ps[1] + ps[2] + ps[3];
    float t2 = ps2[0] + ps2[1] + ps2[2] + ps2[3];
    float mu = t1 * (1.f / 1024.f);
    float var = t2 * (1.f / 1024.f) - mu * mu;
    stats[0] = mu; stats[1] = rsqrtf(var + 1e-5f);
  }
  __syncthreads();
  float mu = stats[0], rs = stats[1];
  fx4 g4 = *reinterpret_cast<const fx4*>(gamma + tid*4);
  fx4 b4 = *reinterpret_cast<const fx4*>(beta + tid*4);
  fx4 o4;
#pragma unroll
  for (int u = 0; u < 4; ++u) o4[u] = (y[u] - mu) * rs * g4[u] + b4[u];
  *reinterpret_cast<fx4*>(orow + tid*4) = o4;
}

extern "C" void kernel_launch(void* const* d_in, const int* in_sizes, int n_in,
                              void* d_out, int out_size, void* d_ws, size_t ws_size,
                              hipStream_t stream) {
  const float* x    = (const float*)d_in[0];
  const float* Wi   = (const float*)d_in[1];
  const float* bi   = (const float*)d_in[2];
  const float* Wf   = (const float*)d_in[3];
  const float* bfv  = (const float*)d_in[4];
  const float* Wg   = (const float*)d_in[5];
  const float* bg   = (const float*)d_in[6];
  const float* Wo   = (const float*)d_in[7];
  const float* bo   = (const float*)d_in[8];
  const float* Weg  = (const float*)d_in[9];
  const float* beg  = (const float*)d_in[10];
  const float* gamma= (const float*)d_in[11];
  const float* beta = (const float*)d_in[12];
  float* out = (float*)d_out;
  char* ws = (char*)d_ws;

  __hip_bfloat16* XG   = (__hip_bfloat16*)(ws);                    // 134217728 B
  __hip_bfloat16* xbf  = (__hip_bfloat16*)(ws + 134217728ull);     //  33554432 B
  __hip_bfloat16* WxT  = (__hip_bfloat16*)(ws + 167772160ull);     //   8388608 B
  __hip_bfloat16* WhT  = (__hip_bfloat16*)(ws + 176160768ull);     //   8388608 B
  __hip_bfloat16* WegT = (__hip_bfloat16*)(ws + 184549376ull);     //   2097152 B
  float* bcat          = (float*)(ws + 186646528ull);              //     16384 B
  u32* h_tag           = (u32*)(ws + 186662912ull);                //     32768 B
  u32* g_tag           = (u32*)(ws + 186695680ull);                //     32768 B

  prep_w<<<dim3(32, 64, 5), dim3(32, 8), 0, stream>>>(Wi, Wf, Wg, Wo, Weg, WxT, WhT, WegT);
  init_k<<<dim3(64), dim3(256), 0, stream>>>(h_tag, g_tag, bi, bfv, bg, bo, bcat);
  conv_x<<<dim3(8192), dim3(256), 0, stream>>>(x, xbf);
  gemm_x<<<dim3(32, 128), dim3(256), 0, stream>>>(xbf, WxT, bcat, XG);
  recur<<<dim3(256), dim3(256), 0, stream>>>(WhT, WegT, XG, beg, h_tag, g_tag, out);
  ln_k<<<dim3(16384), dim3(256), 0, stream>>>(x, gamma, beta, out);
}